// Round 8
// baseline (31.504 us; speedup 1.0000x reference)
//
#include <hip/hip_runtime.h>
#include <math.h>

// BrownianKernelLayer: K[i,j] = 0.5 * sum_d (|x_id|^p + |X2_jd|^p - |x_id - X2_jd|^p)
// p = 2 * softplus(log_H).  N=M=2048, D=16, fp32 in/out.
//
// v8 = single-transcendental term (v5/v7-validated numerics) in the v6
// low-pressure skeleton (64x32 tile, 4x2 micro-tile, unroll 4, 2048 blocks).
//   |u|^p = exp2( p*2^-23 * float(bits(|u|)) + Q(m) ),  m = mantissa in [1,2)
//   Q(m) = p*(log2 m - (m-1)) - 127p, deg-4 runtime Chebyshev fit.
// Per term: sub, and, cvt_f32_u32, and_or, 5 fma, v_exp, add
//         = 10 full-rate VALU + 1 trans   (v6: 3 VALU + 2 trans).
// Discriminator: trans-pipe-bound -> ~14-16 us; issue-blocking -> par (~22).
// u=0 -> bits=0 -> m=1, arg=-127p ~ -215 -> exp2 -> 0 (correct).

#define D_DIM 16
#define BR 64   // rows per tile (x)
#define BC 32   // cols per tile (X2)

__device__ __forceinline__ float powp(float t, float p) {
    return __builtin_amdgcn_exp2f(p * __builtin_amdgcn_logf(t));
}

__global__ __launch_bounds__(256) void fbm_kernel(
    const float* __restrict__ x,    // [N, 16]
    const float* __restrict__ X2,   // [M, 16]
    const float* __restrict__ logH, // [1]
    float* __restrict__ out,        // [N, M]
    int N, int M)
{
    __shared__ float xs[D_DIM][BR];   // transposed x tile
    __shared__ float ys[D_DIM][BC];   // transposed X2 tile
    __shared__ float t1s[BR];
    __shared__ float t2s[BC];

    const int tid  = threadIdx.x;
    const int brow = blockIdx.y * BR;
    const int bcol = blockIdx.x * BC;

    const float H = log1pf(expf(logH[0]));  // softplus(log_H)
    const float p = 2.0f * H;

    // ---- deg-4 Chebyshev fit: phi(m) = log2(m) - (m-1) on [1,2]
    const float T1 = 0.475528258f, T2 = 0.293892626f;
    float n0 = 1.5f + T1, n1 = 1.5f + T2, n2 = 1.5f, n3 = 1.5f - T2, n4 = 1.5f - T1;
    float f0 = __builtin_amdgcn_logf(n0) - (n0 - 1.0f);
    float f1 = __builtin_amdgcn_logf(n1) - (n1 - 1.0f);
    float f2 = __builtin_amdgcn_logf(n2) - (n2 - 1.0f);
    float f3 = __builtin_amdgcn_logf(n3) - (n3 - 1.0f);
    float f4 = __builtin_amdgcn_logf(n4) - (n4 - 1.0f);
    float s1 = 0.5f * (f0 + f4), d1 = 0.5f * (f0 - f4);
    float s2 = 0.5f * (f1 + f3), d2 = 0.5f * (f1 - f3);
    float u1 = T1 * T1, u2 = T2 * T2;
    float A = s1 - f2, B = s2 - f2;
    float det = u1 * u2 * (u2 - u1);
    float e1 = (A * u2 * u2 - B * u1 * u1) / det;
    float e2 = (B * u1 - A * u2) / det;
    float Ap = d1 / T1, Bp = d2 / T2;
    float o1 = (Ap - Bp) / (u1 - u2);
    float o0 = Ap - o1 * u1;
    float a4 = e2;
    float a3 = o1 - 6.0f * e2;
    float a2 = e1 - 4.5f * o1 + 13.5f * e2;
    float a1 = o0 - 3.0f * e1 + 6.75f * o1 - 13.5f * e2;
    float a0 = f2 - 1.5f * o0 + 2.25f * e1 - 3.375f * o1 + 5.0625f * e2;
    // scale by p, fold -127p into constant
    const float q4 = p * a4;
    const float q3 = p * a3;
    const float q2 = p * a2;
    const float q1 = p * a1;
    const float q0 = p * a0 - 127.0f * p;
    const float PB = p * (1.0f / 8388608.0f);   // p * 2^-23

    // ---- stage x tile: 64 rows x 16 d = 1024 floats = 256 x float4
    {
        float4 vx = ((const float4*)(x + (size_t)brow * D_DIM))[tid];
        int r  = tid >> 2;
        int d0 = (tid & 3) << 2;
        xs[d0 + 0][r] = vx.x; xs[d0 + 1][r] = vx.y;
        xs[d0 + 2][r] = vx.z; xs[d0 + 3][r] = vx.w;
    }
    // ---- stage X2 tile: 32 rows x 16 d = 512 floats = 128 x float4
    if (tid < 128) {
        float4 vy = ((const float4*)(X2 + (size_t)bcol * D_DIM))[tid];
        int r  = tid >> 2;
        int d0 = (tid & 3) << 2;
        ys[d0 + 0][r] = vy.x; ys[d0 + 1][r] = vy.y;
        ys[d0 + 2][r] = vy.z; ys[d0 + 3][r] = vy.w;
    }
    __syncthreads();

    // ---- per-row self terms (trans path; negligible count)
    if (tid < BR) {
        float s = 0.0f;
        #pragma unroll
        for (int d = 0; d < D_DIM; ++d) s += powp(fabsf(xs[d][tid]), p);
        t1s[tid] = s;
    } else if (tid < BR + BC) {
        int r = tid - BR;
        float s = 0.0f;
        #pragma unroll
        for (int d = 0; d < D_DIM; ++d) s += powp(fabsf(ys[d][r]), p);
        t2s[r] = s;
    }
    __syncthreads();

    // ---- main: 4x2 outputs per thread; 16x16 thread grid covers 64x32
    const int ti = tid >> 4;
    const int tj = tid & 15;

    float acc[4][2] = {};

    // single-trans |u|^p from bits of |u|
    #define TERM(A_, B_, R_, C_) { \
        float u_ = (A_) - (B_); \
        unsigned ba_ = __float_as_uint(u_) & 0x7FFFFFFFu; \
        float bf_ = (float)ba_; \
        float mm_ = __uint_as_float((ba_ & 0x007FFFFFu) | 0x3F800000u); \
        float ph_ = fmaf(fmaf(fmaf(fmaf(q4, mm_, q3), mm_, q2), mm_, q1), mm_, q0); \
        float arg_ = fmaf(bf_, PB, ph_); \
        acc[R_][C_] += __builtin_amdgcn_exp2f(arg_); }

    #pragma unroll 4
    for (int d = 0; d < D_DIM; ++d) {
        float4 xa = *(const float4*)&xs[d][ti * 4];
        float2 xb = *(const float2*)&ys[d][tj * 2];
        float A0 = xa.x, A1 = xa.y, A2 = xa.z, A3 = xa.w;
        float B0 = xb.x, B1 = xb.y;

        TERM(A0, B0, 0, 0) TERM(A0, B1, 0, 1)
        TERM(A1, B0, 1, 0) TERM(A1, B1, 1, 1)
        TERM(A2, B0, 2, 0) TERM(A2, B1, 2, 1)
        TERM(A3, B0, 3, 0) TERM(A3, B1, 3, 1)
    }
    #undef TERM

    // ---- epilogue: K = 0.5*(t1[i] + t2[j] - t3)
    float t2v0 = t2s[tj * 2 + 0];
    float t2v1 = t2s[tj * 2 + 1];

    #pragma unroll
    for (int a = 0; a < 4; ++a) {
        float t1v = t1s[ti * 4 + a];
        float2 o;
        o.x = 0.5f * (t1v + t2v0 - acc[a][0]);
        o.y = 0.5f * (t1v + t2v1 - acc[a][1]);
        int gi = brow + ti * 4 + a;
        *(float2*)(out + (size_t)gi * M + bcol + tj * 2) = o;
    }
}

extern "C" void kernel_launch(void* const* d_in, const int* in_sizes, int n_in,
                              void* d_out, int out_size, void* d_ws, size_t ws_size,
                              hipStream_t stream) {
    const float* x    = (const float*)d_in[0];
    const float* X2   = (const float*)d_in[1];
    const float* logH = (const float*)d_in[2];
    float* out = (float*)d_out;

    int N = in_sizes[0] / D_DIM;
    int M = in_sizes[1] / D_DIM;

    dim3 grid(M / BC, N / BR);
    dim3 block(256);
    fbm_kernel<<<grid, block, 0, stream>>>(x, X2, logH, out, N, M);
}

// Round 9
// 21.470 us; speedup vs baseline: 1.4674x; 1.4674x over previous
//
#include <hip/hip_runtime.h>
#include <math.h>

// BrownianKernelLayer: K[i,j] = 0.5 * sum_d (|x_id|^p + |X2_jd|^p - |x_id - X2_jd|^p)
// p = 2 * softplus(log_H).  N=M=2048, D=16, fp32 in/out.
//
// v9 = v6 (best: 22.2us, 3 VALU + 2 trans per term, issue-port bound) with the
// three full-rate ops PACKED via VOP3P v_pk_*_f32: per column-PAIR,
//   u2 = pk_sub(broadcast(A), B01); l = log|u.x|,log|u.y|; lv = pk_mul(l, p);
//   e = exp(lv.x),exp(lv.y); acc2 = pk_add(acc2, e)
// -> 1.5 VALU + 2 trans per term (issue-serialized model: 3+2T vs 6+2T cyc).
// Clean A/B vs v6: only the inner loop changed. Predicted -8..-16% if the
// compiler emits pk ops with op_sel broadcast; neutral if it scalarizes.

#define D_DIM 16
#define BR 64   // rows per tile (x)
#define BC 32   // cols per tile (X2)

typedef float v2f __attribute__((ext_vector_type(2)));

__device__ __forceinline__ float powp(float t, float p) {
    return __builtin_amdgcn_exp2f(p * __builtin_amdgcn_logf(t));
}

__global__ __launch_bounds__(256) void fbm_kernel(
    const float* __restrict__ x,    // [N, 16]
    const float* __restrict__ X2,   // [M, 16]
    const float* __restrict__ logH, // [1]
    float* __restrict__ out,        // [N, M]
    int N, int M)
{
    __shared__ float xs[D_DIM][BR];   // transposed x tile
    __shared__ float ys[D_DIM][BC];   // transposed X2 tile
    __shared__ float t1s[BR];
    __shared__ float t2s[BC];

    const int tid  = threadIdx.x;
    const int brow = blockIdx.y * BR;
    const int bcol = blockIdx.x * BC;

    const float p = 2.0f * log1pf(expf(logH[0]));  // 2*softplus

    // ---- stage x tile: 64 rows x 16 d = 1024 floats = 256 x float4
    {
        float4 vx = ((const float4*)(x + (size_t)brow * D_DIM))[tid];
        int r  = tid >> 2;
        int d0 = (tid & 3) << 2;
        xs[d0 + 0][r] = vx.x; xs[d0 + 1][r] = vx.y;
        xs[d0 + 2][r] = vx.z; xs[d0 + 3][r] = vx.w;
    }
    // ---- stage X2 tile: 32 rows x 16 d = 512 floats = 128 x float4
    if (tid < 128) {
        float4 vy = ((const float4*)(X2 + (size_t)bcol * D_DIM))[tid];
        int r  = tid >> 2;
        int d0 = (tid & 3) << 2;
        ys[d0 + 0][r] = vy.x; ys[d0 + 1][r] = vy.y;
        ys[d0 + 2][r] = vy.z; ys[d0 + 3][r] = vy.w;
    }
    __syncthreads();

    // ---- per-row self terms (scalar trans path; negligible count)
    if (tid < BR) {
        float s = 0.0f;
        #pragma unroll
        for (int d = 0; d < D_DIM; ++d) s += powp(fabsf(xs[d][tid]), p);
        t1s[tid] = s;
    } else if (tid < BR + BC) {
        int r = tid - BR;
        float s = 0.0f;
        #pragma unroll
        for (int d = 0; d < D_DIM; ++d) s += powp(fabsf(ys[d][r]), p);
        t2s[r] = s;
    }
    __syncthreads();

    // ---- main: 4x2 outputs per thread; 16x16 thread grid covers 64x32
    const int ti = tid >> 4;
    const int tj = tid & 15;

    const v2f pv = {p, p};
    v2f acc2[4] = {};

    #pragma unroll 4
    for (int d = 0; d < D_DIM; ++d) {
        float4 xa = *(const float4*)&xs[d][ti * 4];
        v2f bv = *(const v2f*)&ys[d][tj * 2];
        float A0 = xa.x, A1 = xa.y, A2 = xa.z, A3 = xa.w;

        #define TERM2(A_, IDX_) { \
            v2f av_; av_.x = (A_); av_.y = (A_); \
            v2f u_ = av_ - bv;                       /* v_pk_add (neg) */ \
            float l0_ = __builtin_amdgcn_logf(__builtin_fabsf(u_.x)); \
            float l1_ = __builtin_amdgcn_logf(__builtin_fabsf(u_.y)); \
            v2f lv_; lv_.x = l0_; lv_.y = l1_; \
            lv_ = lv_ * pv;                          /* v_pk_mul */ \
            float e0_ = __builtin_amdgcn_exp2f(lv_.x); \
            float e1_ = __builtin_amdgcn_exp2f(lv_.y); \
            v2f ev_; ev_.x = e0_; ev_.y = e1_; \
            acc2[IDX_] += ev_;                       /* v_pk_add */ }

        TERM2(A0, 0)
        TERM2(A1, 1)
        TERM2(A2, 2)
        TERM2(A3, 3)
        #undef TERM2
    }

    // ---- epilogue: K = 0.5*(t1[i] + t2[j] - t3)
    float t2v0 = t2s[tj * 2 + 0];
    float t2v1 = t2s[tj * 2 + 1];

    #pragma unroll
    for (int a = 0; a < 4; ++a) {
        float t1v = t1s[ti * 4 + a];
        float2 o;
        o.x = 0.5f * (t1v + t2v0 - acc2[a].x);
        o.y = 0.5f * (t1v + t2v1 - acc2[a].y);
        int gi = brow + ti * 4 + a;
        *(float2*)(out + (size_t)gi * M + bcol + tj * 2) = o;
    }
}

extern "C" void kernel_launch(void* const* d_in, const int* in_sizes, int n_in,
                              void* d_out, int out_size, void* d_ws, size_t ws_size,
                              hipStream_t stream) {
    const float* x    = (const float*)d_in[0];
    const float* X2   = (const float*)d_in[1];
    const float* logH = (const float*)d_in[2];
    float* out = (float*)d_out;

    int N = in_sizes[0] / D_DIM;
    int M = in_sizes[1] / D_DIM;

    dim3 grid(M / BC, N / BR);
    dim3 block(256);
    fbm_kernel<<<grid, block, 0, stream>>>(x, X2, logH, out, N, M);
}